// Round 5
// baseline (2170.734 us; speedup 1.0000x reference)
//
#include <hip/hip_runtime.h>

typedef _Float16 f16;
typedef _Float16 h2 __attribute__((ext_vector_type(2)));
typedef _Float16 h8 __attribute__((ext_vector_type(8)));
typedef _Float16 v8h __attribute__((ext_vector_type(8)));
typedef _Float16 v4h __attribute__((ext_vector_type(4)));
typedef float    f4 __attribute__((ext_vector_type(4)));
typedef float    v4f __attribute__((ext_vector_type(4)));
typedef float    f2 __attribute__((ext_vector_type(2)));

#define S_  256
#define B_  1024
#define D_  64
#define H_  128
#define Z_  32
#define BD_ (B_*D_)
#define NSTEP 514

#define LGKM0 asm volatile("s_waitcnt lgkmcnt(0)" ::: "memory")

__device__ __forceinline__ float fdot2(h2 a, h2 b, float c) {
#if __has_builtin(__builtin_amdgcn_fdot2)
  return __builtin_amdgcn_fdot2(a, b, c, false);
#else
  return c + (float)a[0]*(float)b[0] + (float)a[1]*(float)b[1];
#endif
}

__device__ __forceinline__ float dot8(h8 a, h8 w, float acc) {
  h2 a0 = __builtin_shufflevector(a, a, 0, 1), w0 = __builtin_shufflevector(w, w, 0, 1);
  h2 a1 = __builtin_shufflevector(a, a, 2, 3), w1 = __builtin_shufflevector(w, w, 2, 3);
  h2 a2 = __builtin_shufflevector(a, a, 4, 5), w2 = __builtin_shufflevector(w, w, 4, 5);
  h2 a3 = __builtin_shufflevector(a, a, 6, 7), w3 = __builtin_shufflevector(w, w, 6, 7);
  acc = fdot2(a0, w0, acc);
  acc = fdot2(a1, w1, acc);
  acc = fdot2(a2, w2, acc);
  acc = fdot2(a3, w3, acc);
  return acc;
}

__device__ __forceinline__ h8 ld8(const float* p) {   // 32B-aligned src
  f4 a = *(const f4*)p;
  f4 b = *(const f4*)(p + 4);
  h8 w;
  w[0]=(f16)a[0]; w[1]=(f16)a[1]; w[2]=(f16)a[2]; w[3]=(f16)a[3];
  w[4]=(f16)b[0]; w[5]=(f16)b[1]; w[6]=(f16)b[2]; w[7]=(f16)b[3];
  return w;
}

__device__ __forceinline__ float sigm(float x) { return 1.f / (1.f + __expf(-x)); }
__device__ __forceinline__ float tanh_(float x) {
  float e = __expf(-2.f * fabsf(x));
  float t = (1.f - e) / (1.f + e);
  return copysignf(t, x);
}

// ---------------------------------------------------------------------------
// GRU: round-0 structure (best measured ~628us). UNCHANGED.
// ---------------------------------------------------------------------------
__global__ __launch_bounds__(256, 2) void gru_kernel(
    const float* __restrict__ xs, const float* __restrict__ Wih,
    const float* __restrict__ Whh, const float* __restrict__ bih,
    const float* __restrict__ bhh, float* __restrict__ hT)
{
  __shared__ h8 actH[16][2];               // h f16 [chunk][b]
  __shared__ h8 xv[8][2];                  // x f16 [chunk][b]
  __shared__ float part[2][2][4][128];     // [kh][b][r,z,nh,nx][jh]

  const int t  = threadIdx.x;
  const int b0 = blockIdx.x * 2;
  const int jh = t & 127;
  const int kh = t >> 7;

  h8 whr[8], whz[8], whn[8], wxr[4], wxz[4], wxn[4];
  {
    const float* pr = Whh + jh*H_        + kh*64;
    const float* pz = Whh + (jh+128)*H_  + kh*64;
    const float* pn = Whh + (jh+256)*H_  + kh*64;
    #pragma unroll
    for (int c = 0; c < 8; ++c) {
      whr[c] = ld8(pr + c*8);
      whz[c] = ld8(pz + c*8);
      whn[c] = ld8(pn + c*8);
    }
    const float* qr = Wih + jh*D_        + kh*32;
    const float* qz = Wih + (jh+128)*D_  + kh*32;
    const float* qn = Wih + (jh+256)*D_  + kh*32;
    #pragma unroll
    for (int c = 0; c < 4; ++c) {
      wxr[c] = ld8(qr + c*8);
      wxz[c] = ld8(qz + c*8);
      wxn[c] = ld8(qn + c*8);
    }
  }
  const int gb = t >> 7, hd = t & 127;     // gate-phase role
  const float bir = bih[hd], biz = bih[hd+128], bin = bih[hd+256];
  const float bhr = bhh[hd], bhz = bhh[hd+128], bhn = bhh[hd+256];
  float hmast = 0.f;

  if (t < 32) { h8 zz = {}; actH[t>>1][t&1] = zz; }
  if (t < 128) {
    int b = t >> 6, d = t & 63;
    float x0 = xs[(S_-1)*BD_ + (b0+b)*D_ + d];
    ((f16*)xv)[((d>>3)*2 + b)*8 + (d&7)] = (f16)x0;
  }
  __syncthreads();

  #pragma unroll 1
  for (int s = 0; s < S_; ++s) {
    float xnext = 0.f;
    if (s < S_-1 && t < 128) {
      int b = t >> 6, d = t & 63;
      xnext = xs[(S_-2-s)*BD_ + (b0+b)*D_ + d];
    }
    float pr0=0.f, pz0=0.f, pnh0=0.f, pnx0=0.f;
    float pr1=0.f, pz1=0.f, pnh1=0.f, pnx1=0.f;
    #pragma unroll
    for (int c = 0; c < 8; ++c) {
      h8 a0 = actH[kh*8 + c][0];
      h8 a1 = actH[kh*8 + c][1];
      pr0  = dot8(a0, whr[c], pr0);   pr1  = dot8(a1, whr[c], pr1);
      pz0  = dot8(a0, whz[c], pz0);   pz1  = dot8(a1, whz[c], pz1);
      pnh0 = dot8(a0, whn[c], pnh0);  pnh1 = dot8(a1, whn[c], pnh1);
    }
    #pragma unroll
    for (int c = 0; c < 4; ++c) {
      h8 a0 = xv[kh*4 + c][0];
      h8 a1 = xv[kh*4 + c][1];
      pr0  = dot8(a0, wxr[c], pr0);   pr1  = dot8(a1, wxr[c], pr1);
      pz0  = dot8(a0, wxz[c], pz0);   pz1  = dot8(a1, wxz[c], pz1);
      pnx0 = dot8(a0, wxn[c], pnx0);  pnx1 = dot8(a1, wxn[c], pnx1);
    }
    part[kh][0][0][jh] = pr0;   part[kh][1][0][jh] = pr1;
    part[kh][0][1][jh] = pz0;   part[kh][1][1][jh] = pz1;
    part[kh][0][2][jh] = pnh0;  part[kh][1][2][jh] = pnh1;
    part[kh][0][3][jh] = pnx0;  part[kh][1][3][jh] = pnx1;
    __syncthreads();

    {
      float pr  = part[0][gb][0][hd] + part[1][gb][0][hd];
      float pz  = part[0][gb][1][hd] + part[1][gb][1][hd];
      float pnh = part[0][gb][2][hd] + part[1][gb][2][hd];
      float pnx = part[0][gb][3][hd] + part[1][gb][3][hd];
      float r  = sigm(pr + bir + bhr);
      float zg = sigm(pz + biz + bhz);
      float n  = tanh_(pnx + bin + r*(pnh + bhn));
      hmast = (1.f - zg)*n + zg*hmast;
      ((f16*)actH)[((hd>>3)*2 + gb)*8 + (hd&7)] = (f16)hmast;
    }
    if (s < S_-1 && t < 128) {
      int b = t >> 6, d = t & 63;
      ((f16*)xv)[((d>>3)*2 + b)*8 + (d&7)] = (f16)xnext;
    }
    __syncthreads();
  }
  hT[(b0 + gb)*H_ + hd] = hmast;
}

// ---------------------------------------------------------------------------
// Encoder head (unchanged; tiny): 256 blocks x 4 rows.
// ---------------------------------------------------------------------------
__global__ __launch_bounds__(256) void enc_kernel(
    const float* __restrict__ hT, const float* __restrict__ encW,
    const float* __restrict__ encB, const float* __restrict__ qW,
    const float* __restrict__ qB, const float* __restrict__ eps,
    const float* __restrict__ pm, const float* __restrict__ pls,
    float* __restrict__ z0, float* __restrict__ out)
{
  __shared__ float hTl[4][128];
  __shared__ float ctx[4][64];
  __shared__ float ql[4][64];
  const int t = threadIdx.x;
  const int b0 = blockIdx.x * 4;
  const int lb = t >> 6, j = t & 63;

  for (int i = t; i < 512; i += 256) hTl[i>>7][i&127] = hT[b0*H_ + i];
  __syncthreads();

  float acc = encB[j];
  #pragma unroll
  for (int k = 0; k < 128; k += 4) {
    f4 w = *(const f4*)&encW[j*128 + k];
    acc += hTl[lb][k]*w[0] + hTl[lb][k+1]*w[1] + hTl[lb][k+2]*w[2] + hTl[lb][k+3]*w[3];
  }
  ctx[lb][j] = acc;
  __syncthreads();

  float q = qB[j];
  #pragma unroll
  for (int k = 0; k < 64; k += 4) {
    f4 w = *(const f4*)&qW[j*64 + k];
    q += ctx[lb][k]*w[0] + ctx[lb][k+1]*w[1] + ctx[lb][k+2]*w[2] + ctx[lb][k+3]*w[3];
  }
  ql[lb][j] = q;
  __syncthreads();

  float kl = 0.f;
  if (j < 32) {
    float mean = ql[lb][j], ls = ql[lb][j+32];
    z0[(b0+lb)*Z_ + j] = mean + __expf(ls)*eps[(b0+lb)*Z_ + j];
    float pmj = pm[j], plsj = pls[j];
    float dm = mean - pmj;
    kl = plsj - ls + (__expf(2.f*ls) + dm*dm) / (2.f*__expf(2.f*plsj)) - 0.5f;
  }
  #pragma unroll
  for (int s2 = 32; s2 > 0; s2 >>= 1) kl += __shfl_down(kl, s2, 64);
  if (j == 0) atomicAdd(out + 1, kl * (1.f/1024.f));
}

// ---------------------------------------------------------------------------
// SDE round-5: MFMA rewrite. 64 blocks x 1 wave (64 threads), 16 batch rows
// per block. Computes OUT^T = W @ ACT^T so that:
//   A-frag (weights): lane holds row (l&15), k (l>>4)*8+j  — W1/W2 in VGPRs,
//                     W3|gW2|pW frag-major in LDS (lane-sequential b128 reads)
//   B-frag (acts):    lane holds batch col (l&15), k (l>>4)*8+j — contiguous
//                     16B reads from [batch][k] row-major f16 LDS
//   C/D (m89-verified): col=lane&15=batch, row=(lane>>4)*4+i=out-neuron ->
//                     each lane's 4 outputs are CONSECUTIVE k of the next
//                     layer -> single 8B ds_write per tile.
// Bias/t folded as K-columns (X: col32=t, col33=1, col34=t-f16-residual;
// h arrays: col128=1). Zero barriers: single wave, s_waitcnt lgkmcnt(0) only.
// z master fp32 lives in exactly the lanes that compute the update.
// ---------------------------------------------------------------------------
__global__ __launch_bounds__(64, 1) void sde_mfma_kernel(
    const float* __restrict__ z0, const float* __restrict__ ts,
    const float* __restrict__ dW, const float* __restrict__ xs,
    const float* __restrict__ fW1, const float* __restrict__ fb1,
    const float* __restrict__ fW2, const float* __restrict__ fb2,
    const float* __restrict__ fW3, const float* __restrict__ fb3,
    const float* __restrict__ gW1, const float* __restrict__ gb1,
    const float* __restrict__ gW2, const float* __restrict__ gb2,
    const float* __restrict__ pW, const float* __restrict__ pb,
    float* __restrict__ out)
{
  __shared__ f16 Wlds[112*128];   // chunks 0..79: [fW3;gW2] (4 tiles x 20 kb), 80..111: pW (4 x 8)
  __shared__ f16 Xa[16*72];       // [batch][72]: 0..31 z, 32 t, 33 one, 34 t-resid, rest 0
  __shared__ f16 h1A[16*168];     // [batch][168]: 0..127 h1, 128 one, 129.. 0
  __shared__ f16 ghA[16*168];
  __shared__ f16 h2A[16*168];
  __shared__ float tsL[516];

  const int lane = threadIdx.x;
  const int lr = lane & 15;       // tile-row / batch-col index
  const int lg = lane >> 4;       // k-group
  const int r0 = blockIdx.x * 16;

  // ---- stage W1pad (f+g, K=64) into regs: 32 frags = 128 VGPR
  v8h w1r[32];
  #pragma unroll
  for (int n = 0; n < 16; ++n) {
    const float* src = (n < 8) ? (fW1 + (n*16+lr)*33) : (gW1 + ((n-8)*16+lr)*33);
    const float bsv  = (n < 8) ? fb1[n*16+lr] : gb1[(n-8)*16+lr];
    #pragma unroll
    for (int ks = 0; ks < 2; ++ks) {
      v8h w;
      #pragma unroll
      for (int j = 0; j < 8; ++j) {
        const int kp = ks*32 + lg*8 + j;
        float v;
        if (kp < 32)                 v = src[1+kp];
        else if (kp == 32 || kp == 34) v = src[0];
        else if (kp == 33)           v = bsv;
        else                         v = 0.f;
        w[j] = (f16)v;
      }
      w1r[n*2+ks] = w;
    }
  }
  // ---- stage W2pad (K=160) into regs: 40 frags = 160 VGPR
  v8h w2r[40];
  #pragma unroll
  for (int n = 0; n < 8; ++n) {
    const float* src = fW2 + (n*16+lr)*128;
    const float bsv = fb2[n*16+lr];
    #pragma unroll
    for (int ks = 0; ks < 5; ++ks) {
      v8h w;
      #pragma unroll
      for (int j = 0; j < 8; ++j) {
        const int kp = ks*32 + lg*8 + j;
        float v = (kp < 128) ? src[kp] : ((kp == 128) ? bsv : 0.f);
        w[j] = (f16)v;
      }
      w2r[n*5+ks] = w;
    }
  }
  // ---- stage [fW3;gW2] pad (K=160) frag-major in LDS
  for (int idx = lane; idx < 80*128; idx += 64) {
    const int j = idx & 7, r = (idx >> 3) & 15, c = idx >> 7;
    const int kb = c % 20, n = c / 20;
    const int kp = kb*8 + j;
    float v;
    if (n < 2) v = (kp < 128) ? fW3[(n*16+r)*128 + kp] : ((kp == 128) ? fb3[n*16+r] : 0.f);
    else       v = (kp < 128) ? gW2[((n-2)*16+r)*128 + kp] : ((kp == 128) ? gb2[(n-2)*16+r] : 0.f);
    Wlds[c*128 + r*8 + j] = (f16)v;
  }
  // ---- stage pWpad (K=64: 0..31 z, 33 bias) frag-major in LDS
  for (int idx = lane; idx < 32*128; idx += 64) {
    const int j = idx & 7, r = (idx >> 3) & 15, c = idx >> 7;
    const int kb = c & 7, n = c >> 3;
    const int kp = kb*8 + j;
    float v = (kp < 32) ? pW[(n*16+r)*32 + kp] : ((kp == 33) ? pb[n*16+r] : 0.f);
    Wlds[(80 + c)*128 + r*8 + j] = (f16)v;
  }
  // ---- init activations
  for (int i = lane; i < 16*72; i += 64) Xa[i] = (f16)0.f;
  for (int i = lane; i < 16*168; i += 64) {
    h1A[i] = (f16)0.f; ghA[i] = (f16)0.f; h2A[i] = (f16)0.f;
  }
  for (int i = lane; i < 515; i += 64) tsL[i] = ts[i];
  LGKM0;
  if (lane < 16) {
    Xa[lane*72 + 33] = (f16)1.f;
    h1A[lane*168 + 128] = (f16)1.f;
    ghA[lane*168 + 128] = (f16)1.f;
    h2A[lane*168 + 128] = (f16)1.f;
  }
  // z0 -> fp32 masters (lane owns batch lr, z dims lg*4+i and 16+lg*4+i) + Xa
  v4f zm0 = *(const v4f*)&z0[(r0+lr)*Z_ + lg*4];
  v4f zm1 = *(const v4f*)&z0[(r0+lr)*Z_ + 16 + lg*4];
  {
    v4h a, b;
    #pragma unroll
    for (int i = 0; i < 4; ++i) { a[i] = (f16)zm0[i]; b[i] = (f16)zm1[i]; }
    *(v4h*)&Xa[lr*72 + lg*4] = a;
    *(v4h*)&Xa[lr*72 + 16 + lg*4] = b;
  }
  float loss = 0.f;
  const v4f zero4 = {0.f, 0.f, 0.f, 0.f};
  LGKM0;

  #pragma unroll 1
  for (int l = 0; l < NSTEP; ++l) {
    const float tl  = tsL[l];
    const float dt  = tsL[l+1] - tl;
    const float sdt = sqrtf(dt);
    const int ln = l + 1;
    const bool ev = ((ln & 1) == 0) && ln >= 2 && ln <= 512;
    const bool od = ((ln & 1) == 1) && ln >= 3 && ln <= 511;

    // prefetch globals (used near end of step)
    const v4f dw0 = *(const v4f*)&dW[(l*B_ + r0 + lr)*Z_ + lg*4];
    const v4f dw1 = *(const v4f*)&dW[(l*B_ + r0 + lr)*Z_ + 16 + lg*4];
    v4f x0 = zero4, x1 = zero4, x2 = zero4, x3 = zero4;
    if (ev) {
      const int si = (ln - 2) >> 1;
      const float* xp = xs + (si*B_ + r0 + lr)*D_;
      x0 = *(const v4f*)&xp[ 0 + lg*4];
      x1 = *(const v4f*)&xp[16 + lg*4];
      x2 = *(const v4f*)&xp[32 + lg*4];
      x3 = *(const v4f*)&xp[48 + lg*4];
    }

    // write t and t-residual columns for this step
    if (lane < 16) {
      const f16 th = (f16)tl;
      Xa[lane*72 + 32] = th;
      Xa[lane*72 + 34] = (f16)(tl - (float)th);
    }
    LGKM0;

    // ---- GEMM1: [h1; gh]^T = W1pad @ X^T   (16 tiles x 2 k-steps)
    {
      const v8h bx0 = *(const v8h*)&Xa[lr*72 +  0 + lg*8];
      const v8h bx1 = *(const v8h*)&Xa[lr*72 + 32 + lg*8];
      #pragma unroll
      for (int n = 0; n < 16; ++n) {
        v4f acc = __builtin_amdgcn_mfma_f32_16x16x32_f16(w1r[n*2+0], bx0, zero4, 0, 0, 0);
        acc = __builtin_amdgcn_mfma_f32_16x16x32_f16(w1r[n*2+1], bx1, acc, 0, 0, 0);
        v4h o;
        #pragma unroll
        for (int i = 0; i < 4; ++i) o[i] = (f16)fmaxf(acc[i], 0.f);
        if (n < 8) *(v4h*)&h1A[lr*168 + n*16 + lg*4] = o;
        else       *(v4h*)&ghA[lr*168 + (n-8)*16 + lg*4] = o;
      }
    }
    LGKM0;

    // ---- GEMM2: h2^T = W2pad @ h1pad^T   (8 tiles x 5 k-steps)
    {
      v8h bh[5];
      #pragma unroll
      for (int ks = 0; ks < 5; ++ks) bh[ks] = *(const v8h*)&h1A[lr*168 + ks*32 + lg*8];
      #pragma unroll
      for (int n = 0; n < 8; ++n) {
        v4f acc = zero4;
        #pragma unroll
        for (int ks = 0; ks < 5; ++ks)
          acc = __builtin_amdgcn_mfma_f32_16x16x32_f16(w2r[n*5+ks], bh[ks], acc, 0, 0, 0);
        v4h o;
        #pragma unroll
        for (int i = 0; i < 4; ++i) o[i] = (f16)fmaxf(acc[i], 0.f);
        *(v4h*)&h2A[lr*168 + n*16 + lg*4] = o;
      }
    }
    LGKM0;

    // ---- GEMM3: drift^T = fW3pad @ h2pad^T; diff^T = gW2pad @ ghpad^T
    v4f dac0 = zero4, dac1 = zero4, fac0 = zero4, fac1 = zero4;
    #pragma unroll
    for (int ks = 0; ks < 5; ++ks) {
      const v8h b2f = *(const v8h*)&h2A[lr*168 + ks*32 + lg*8];
      const v8h bgf = *(const v8h*)&ghA[lr*168 + ks*32 + lg*8];
      const v8h wd0 = *(const v8h*)&Wlds[(0*20 + ks*4 + lg)*128 + lr*8];
      const v8h wd1 = *(const v8h*)&Wlds[(1*20 + ks*4 + lg)*128 + lr*8];
      const v8h wg0 = *(const v8h*)&Wlds[(2*20 + ks*4 + lg)*128 + lr*8];
      const v8h wg1 = *(const v8h*)&Wlds[(3*20 + ks*4 + lg)*128 + lr*8];
      dac0 = __builtin_amdgcn_mfma_f32_16x16x32_f16(wd0, b2f, dac0, 0, 0, 0);
      dac1 = __builtin_amdgcn_mfma_f32_16x16x32_f16(wd1, b2f, dac1, 0, 0, 0);
      fac0 = __builtin_amdgcn_mfma_f32_16x16x32_f16(wg0, bgf, fac0, 0, 0, 0);
      fac1 = __builtin_amdgcn_mfma_f32_16x16x32_f16(wg1, bgf, fac1, 0, 0, 0);
    }

    // ---- z update in fp32 masters, write f16 z back to Xa
    #pragma unroll
    for (int i = 0; i < 4; ++i) {
      zm0[i] += dac0[i]*dt + fac0[i]*(sdt*dw0[i]);
      zm1[i] += dac1[i]*dt + fac1[i]*(sdt*dw1[i]);
    }
    {
      v4h a, b;
      #pragma unroll
      for (int i = 0; i < 4; ++i) { a[i] = (f16)zm0[i]; b[i] = (f16)zm1[i]; }
      *(v4h*)&Xa[lr*72 + lg*4] = a;
      *(v4h*)&Xa[lr*72 + 16 + lg*4] = b;
    }
    LGKM0;

    // ---- proj: xhat^T = pWpad @ [z,1]^T  (4 tiles x 2 k-steps)
    if (ev || od) {
      const v8h px0 = *(const v8h*)&Xa[lr*72 +  0 + lg*8];
      const v8h px1 = *(const v8h*)&Xa[lr*72 + 32 + lg*8];
      v4f p0, p1, p2, p3;
      {
        v4f a;
        a = __builtin_amdgcn_mfma_f32_16x16x32_f16(*(const v8h*)&Wlds[(80 + 0*8 + 0 + lg)*128 + lr*8], px0, zero4, 0,0,0);
        p0 = __builtin_amdgcn_mfma_f32_16x16x32_f16(*(const v8h*)&Wlds[(80 + 0*8 + 4 + lg)*128 + lr*8], px1, a, 0,0,0);
        a = __builtin_amdgcn_mfma_f32_16x16x32_f16(*(const v8h*)&Wlds[(80 + 1*8 + 0 + lg)*128 + lr*8], px0, zero4, 0,0,0);
        p1 = __builtin_amdgcn_mfma_f32_16x16x32_f16(*(const v8h*)&Wlds[(80 + 1*8 + 4 + lg)*128 + lr*8], px1, a, 0,0,0);
        a = __builtin_amdgcn_mfma_f32_16x16x32_f16(*(const v8h*)&Wlds[(80 + 2*8 + 0 + lg)*128 + lr*8], px0, zero4, 0,0,0);
        p2 = __builtin_amdgcn_mfma_f32_16x16x32_f16(*(const v8h*)&Wlds[(80 + 2*8 + 4 + lg)*128 + lr*8], px1, a, 0,0,0);
        a = __builtin_amdgcn_mfma_f32_16x16x32_f16(*(const v8h*)&Wlds[(80 + 3*8 + 0 + lg)*128 + lr*8], px0, zero4, 0,0,0);
        p3 = __builtin_amdgcn_mfma_f32_16x16x32_f16(*(const v8h*)&Wlds[(80 + 3*8 + 4 + lg)*128 + lr*8], px1, a, 0,0,0);
      }
      if (ev) {
        #pragma unroll
        for (int i = 0; i < 4; ++i) {
          float d0 = p0[i] - x0[i]; loss = fmaf(d0, d0, loss);
          float d1 = p1[i] - x1[i]; loss = fmaf(d1, d1, loss);
          float d2 = p2[i] - x2[i]; loss = fmaf(d2, d2, loss);
          float d3 = p3[i] - x3[i]; loss = fmaf(d3, d3, loss);
        }
      } else {
        const int si2 = (ln - 3) >> 1;
        float* op = out + 2 + (si2*B_ + r0 + lr)*D_ + lg*4;
        *(f2*)&op[ 0] = (f2){p0[0], p0[1]};  *(f2*)&op[ 2] = (f2){p0[2], p0[3]};
        *(f2*)&op[16] = (f2){p1[0], p1[1]};  *(f2*)&op[18] = (f2){p1[2], p1[3]};
        *(f2*)&op[32] = (f2){p2[0], p2[1]};  *(f2*)&op[34] = (f2){p2[2], p2[3]};
        *(f2*)&op[48] = (f2){p3[0], p3[1]};  *(f2*)&op[50] = (f2){p3[2], p3[3]};
      }
    }
  }

  #pragma unroll
  for (int s2 = 32; s2 > 0; s2 >>= 1) loss += __shfl_down(loss, s2, 64);
  if (lane == 0) atomicAdd(out + 0, loss * (1.f/16777216.f));
}

extern "C" void kernel_launch(void* const* d_in, const int* in_sizes, int n_in,
                              void* d_out, int out_size, void* d_ws, size_t ws_size,
                              hipStream_t stream) {
  (void)in_sizes; (void)n_in; (void)out_size; (void)ws_size;
  const float* xs   = (const float*)d_in[0];
  const float* ts   = (const float*)d_in[1];
  const float* eps  = (const float*)d_in[2];
  const float* dWp  = (const float*)d_in[3];
  const float* Wih  = (const float*)d_in[4];
  const float* Whh  = (const float*)d_in[5];
  const float* bih  = (const float*)d_in[6];
  const float* bhh  = (const float*)d_in[7];
  const float* encW = (const float*)d_in[8];
  const float* encB = (const float*)d_in[9];
  const float* qW   = (const float*)d_in[10];
  const float* qB   = (const float*)d_in[11];
  const float* fW1  = (const float*)d_in[12];
  const float* fb1  = (const float*)d_in[13];
  const float* fW2  = (const float*)d_in[14];
  const float* fb2  = (const float*)d_in[15];
  const float* fW3  = (const float*)d_in[16];
  const float* fb3  = (const float*)d_in[17];
  const float* gW1  = (const float*)d_in[18];
  const float* gb1  = (const float*)d_in[19];
  const float* gW2  = (const float*)d_in[20];
  const float* gb2  = (const float*)d_in[21];
  const float* pW   = (const float*)d_in[22];
  const float* pb   = (const float*)d_in[23];
  const float* pm   = (const float*)d_in[24];
  const float* pls  = (const float*)d_in[25];

  float* out = (float*)d_out;
  float* ws  = (float*)d_ws;
  float* hT = ws;              // 1024*128 floats
  float* z0 = ws + 131072;     // 1024*32 floats

  hipMemsetAsync(d_out, 0, 2*sizeof(float), stream);
  hipLaunchKernelGGL(gru_kernel, dim3(512), dim3(256), 0, stream,
                     xs, Wih, Whh, bih, bhh, hT);
  hipLaunchKernelGGL(enc_kernel, dim3(256), dim3(256), 0, stream,
                     hT, encW, encB, qW, qB, eps, pm, pls, z0, out);
  hipLaunchKernelGGL(sde_mfma_kernel, dim3(64), dim3(64), 0, stream,
                     z0, ts, dWp, xs, fW1, fb1, fW2, fb2, fW3, fb3,
                     gW1, gb1, gW2, gb2, pW, pb, out);
}

// Round 6
// 1278.122 us; speedup vs baseline: 1.6984x; 1.6984x over previous
//
#include <hip/hip_runtime.h>

typedef _Float16 f16;
typedef _Float16 h2 __attribute__((ext_vector_type(2)));
typedef _Float16 h8 __attribute__((ext_vector_type(8)));
typedef _Float16 v8h __attribute__((ext_vector_type(8)));
typedef _Float16 v4h __attribute__((ext_vector_type(4)));
typedef float    f4 __attribute__((ext_vector_type(4)));
typedef float    v4f __attribute__((ext_vector_type(4)));
typedef float    f2 __attribute__((ext_vector_type(2)));

#define S_  256
#define B_  1024
#define D_  64
#define H_  128
#define Z_  32
#define BD_ (B_*D_)
#define NSTEP 514

__device__ __forceinline__ float fdot2(h2 a, h2 b, float c) {
#if __has_builtin(__builtin_amdgcn_fdot2)
  return __builtin_amdgcn_fdot2(a, b, c, false);
#else
  return c + (float)a[0]*(float)b[0] + (float)a[1]*(float)b[1];
#endif
}

__device__ __forceinline__ float dot8(h8 a, h8 w, float acc) {
  h2 a0 = __builtin_shufflevector(a, a, 0, 1), w0 = __builtin_shufflevector(w, w, 0, 1);
  h2 a1 = __builtin_shufflevector(a, a, 2, 3), w1 = __builtin_shufflevector(w, w, 2, 3);
  h2 a2 = __builtin_shufflevector(a, a, 4, 5), w2 = __builtin_shufflevector(w, w, 4, 5);
  h2 a3 = __builtin_shufflevector(a, a, 6, 7), w3 = __builtin_shufflevector(w, w, 6, 7);
  acc = fdot2(a0, w0, acc);
  acc = fdot2(a1, w1, acc);
  acc = fdot2(a2, w2, acc);
  acc = fdot2(a3, w3, acc);
  return acc;
}

__device__ __forceinline__ h8 ld8(const float* p) {   // 32B-aligned src
  f4 a = *(const f4*)p;
  f4 b = *(const f4*)(p + 4);
  h8 w;
  w[0]=(f16)a[0]; w[1]=(f16)a[1]; w[2]=(f16)a[2]; w[3]=(f16)a[3];
  w[4]=(f16)b[0]; w[5]=(f16)b[1]; w[6]=(f16)b[2]; w[7]=(f16)b[3];
  return w;
}

__device__ __forceinline__ float sigm(float x) { return 1.f / (1.f + __expf(-x)); }
__device__ __forceinline__ float tanh_(float x) {
  float e = __expf(-2.f * fabsf(x));
  float t = (1.f - e) / (1.f + e);
  return copysignf(t, x);
}

// ---------------------------------------------------------------------------
// GRU: round-0 structure (best measured ~628us). UNCHANGED.
// ---------------------------------------------------------------------------
__global__ __launch_bounds__(256, 2) void gru_kernel(
    const float* __restrict__ xs, const float* __restrict__ Wih,
    const float* __restrict__ Whh, const float* __restrict__ bih,
    const float* __restrict__ bhh, float* __restrict__ hT)
{
  __shared__ h8 actH[16][2];               // h f16 [chunk][b]
  __shared__ h8 xv[8][2];                  // x f16 [chunk][b]
  __shared__ float part[2][2][4][128];     // [kh][b][r,z,nh,nx][jh]

  const int t  = threadIdx.x;
  const int b0 = blockIdx.x * 2;
  const int jh = t & 127;
  const int kh = t >> 7;

  h8 whr[8], whz[8], whn[8], wxr[4], wxz[4], wxn[4];
  {
    const float* pr = Whh + jh*H_        + kh*64;
    const float* pz = Whh + (jh+128)*H_  + kh*64;
    const float* pn = Whh + (jh+256)*H_  + kh*64;
    #pragma unroll
    for (int c = 0; c < 8; ++c) {
      whr[c] = ld8(pr + c*8);
      whz[c] = ld8(pz + c*8);
      whn[c] = ld8(pn + c*8);
    }
    const float* qr = Wih + jh*D_        + kh*32;
    const float* qz = Wih + (jh+128)*D_  + kh*32;
    const float* qn = Wih + (jh+256)*D_  + kh*32;
    #pragma unroll
    for (int c = 0; c < 4; ++c) {
      wxr[c] = ld8(qr + c*8);
      wxz[c] = ld8(qz + c*8);
      wxn[c] = ld8(qn + c*8);
    }
  }
  const int gb = t >> 7, hd = t & 127;     // gate-phase role
  const float bir = bih[hd], biz = bih[hd+128], bin = bih[hd+256];
  const float bhr = bhh[hd], bhz = bhh[hd+128], bhn = bhh[hd+256];
  float hmast = 0.f;

  if (t < 32) { h8 zz = {}; actH[t>>1][t&1] = zz; }
  if (t < 128) {
    int b = t >> 6, d = t & 63;
    float x0 = xs[(S_-1)*BD_ + (b0+b)*D_ + d];
    ((f16*)xv)[((d>>3)*2 + b)*8 + (d&7)] = (f16)x0;
  }
  __syncthreads();

  #pragma unroll 1
  for (int s = 0; s < S_; ++s) {
    float xnext = 0.f;
    if (s < S_-1 && t < 128) {
      int b = t >> 6, d = t & 63;
      xnext = xs[(S_-2-s)*BD_ + (b0+b)*D_ + d];
    }
    float pr0=0.f, pz0=0.f, pnh0=0.f, pnx0=0.f;
    float pr1=0.f, pz1=0.f, pnh1=0.f, pnx1=0.f;
    #pragma unroll
    for (int c = 0; c < 8; ++c) {
      h8 a0 = actH[kh*8 + c][0];
      h8 a1 = actH[kh*8 + c][1];
      pr0  = dot8(a0, whr[c], pr0);   pr1  = dot8(a1, whr[c], pr1);
      pz0  = dot8(a0, whz[c], pz0);   pz1  = dot8(a1, whz[c], pz1);
      pnh0 = dot8(a0, whn[c], pnh0);  pnh1 = dot8(a1, whn[c], pnh1);
    }
    #pragma unroll
    for (int c = 0; c < 4; ++c) {
      h8 a0 = xv[kh*4 + c][0];
      h8 a1 = xv[kh*4 + c][1];
      pr0  = dot8(a0, wxr[c], pr0);   pr1  = dot8(a1, wxr[c], pr1);
      pz0  = dot8(a0, wxz[c], pz0);   pz1  = dot8(a1, wxz[c], pz1);
      pnx0 = dot8(a0, wxn[c], pnx0);  pnx1 = dot8(a1, wxn[c], pnx1);
    }
    part[kh][0][0][jh] = pr0;   part[kh][1][0][jh] = pr1;
    part[kh][0][1][jh] = pz0;   part[kh][1][1][jh] = pz1;
    part[kh][0][2][jh] = pnh0;  part[kh][1][2][jh] = pnh1;
    part[kh][0][3][jh] = pnx0;  part[kh][1][3][jh] = pnx1;
    __syncthreads();

    {
      float pr  = part[0][gb][0][hd] + part[1][gb][0][hd];
      float pz  = part[0][gb][1][hd] + part[1][gb][1][hd];
      float pnh = part[0][gb][2][hd] + part[1][gb][2][hd];
      float pnx = part[0][gb][3][hd] + part[1][gb][3][hd];
      float r  = sigm(pr + bir + bhr);
      float zg = sigm(pz + biz + bhz);
      float n  = tanh_(pnx + bin + r*(pnh + bhn));
      hmast = (1.f - zg)*n + zg*hmast;
      ((f16*)actH)[((hd>>3)*2 + gb)*8 + (hd&7)] = (f16)hmast;
    }
    if (s < S_-1 && t < 128) {
      int b = t >> 6, d = t & 63;
      ((f16*)xv)[((d>>3)*2 + b)*8 + (d&7)] = (f16)xnext;
    }
    __syncthreads();
  }
  hT[(b0 + gb)*H_ + hd] = hmast;
}

// ---------------------------------------------------------------------------
// Encoder head (unchanged; tiny): 256 blocks x 4 rows.
// ---------------------------------------------------------------------------
__global__ __launch_bounds__(256) void enc_kernel(
    const float* __restrict__ hT, const float* __restrict__ encW,
    const float* __restrict__ encB, const float* __restrict__ qW,
    const float* __restrict__ qB, const float* __restrict__ eps,
    const float* __restrict__ pm, const float* __restrict__ pls,
    float* __restrict__ z0, float* __restrict__ out)
{
  __shared__ float hTl[4][128];
  __shared__ float ctx[4][64];
  __shared__ float ql[4][64];
  const int t = threadIdx.x;
  const int b0 = blockIdx.x * 4;
  const int lb = t >> 6, j = t & 63;

  for (int i = t; i < 512; i += 256) hTl[i>>7][i&127] = hT[b0*H_ + i];
  __syncthreads();

  float acc = encB[j];
  #pragma unroll
  for (int k = 0; k < 128; k += 4) {
    f4 w = *(const f4*)&encW[j*128 + k];
    acc += hTl[lb][k]*w[0] + hTl[lb][k+1]*w[1] + hTl[lb][k+2]*w[2] + hTl[lb][k+3]*w[3];
  }
  ctx[lb][j] = acc;
  __syncthreads();

  float q = qB[j];
  #pragma unroll
  for (int k = 0; k < 64; k += 4) {
    f4 w = *(const f4*)&qW[j*64 + k];
    q += ctx[lb][k]*w[0] + ctx[lb][k+1]*w[1] + ctx[lb][k+2]*w[2] + ctx[lb][k+3]*w[3];
  }
  ql[lb][j] = q;
  __syncthreads();

  float kl = 0.f;
  if (j < 32) {
    float mean = ql[lb][j], ls = ql[lb][j+32];
    z0[(b0+lb)*Z_ + j] = mean + __expf(ls)*eps[(b0+lb)*Z_ + j];
    float pmj = pm[j], plsj = pls[j];
    float dm = mean - pmj;
    kl = plsj - ls + (__expf(2.f*ls) + dm*dm) / (2.f*__expf(2.f*plsj)) - 0.5f;
  }
  #pragma unroll
  for (int s2 = 32; s2 > 0; s2 >>= 1) kl += __shfl_down(kl, s2, 64);
  if (j == 0) atomicAdd(out + 1, kl * (1.f/1024.f));
}

// ---------------------------------------------------------------------------
// SDE round-6: MFMA, 64 blocks x 4 WAVES (256 thr). Verified r5 fragment
// layouts kept; neuron-dim tiles split across waves:
//   GEMM1 16 tiles -> 4/wave (waves 0,1 h1; waves 2,3 gh)
//   GEMM2  8 tiles -> 2/wave
//   phase3: wave w in {0,1} computes BOTH drift & diff for z-half w
//           (10 MFMA) and updates zm in-register; wave 3 writes next-step
//           t-columns; no cross-wave exchange needed
//   proj:   4 tiles -> 1/wave (after B3; barrier-free vs next GEMM1 — Xa
//           is only rewritten after the next step's B2)
// All weights in VGPRs (~120 regs of frags), activations in LDS.
// 3 __syncthreads()/step. launch_bounds(256,1): 512-VGPR budget, no spill.
// ---------------------------------------------------------------------------
__global__ __launch_bounds__(256, 1) void sde_mfma_kernel(
    const float* __restrict__ z0, const float* __restrict__ ts,
    const float* __restrict__ dW, const float* __restrict__ xs,
    const float* __restrict__ fW1, const float* __restrict__ fb1,
    const float* __restrict__ fW2, const float* __restrict__ fb2,
    const float* __restrict__ fW3, const float* __restrict__ fb3,
    const float* __restrict__ gW1, const float* __restrict__ gb1,
    const float* __restrict__ gW2, const float* __restrict__ gb2,
    const float* __restrict__ pW, const float* __restrict__ pb,
    float* __restrict__ out)
{
  __shared__ f16 Xa[16*72];       // [batch][72]: 0..31 z, 32 t, 33 one, 34 t-resid
  __shared__ f16 h1A[16*168];     // [batch][168]: 0..127 h1, 128 one, rest 0
  __shared__ f16 ghA[16*168];
  __shared__ f16 h2A[16*168];
  __shared__ float tsL[516];
  __shared__ float lred[4];

  const int t    = threadIdx.x;
  const int wid  = t >> 6;
  const int lane = t & 63;
  const int lr = lane & 15;       // tile-row (A) / batch-col (B/C)
  const int lg = lane >> 4;       // k-group / C row-group
  const int r0 = blockIdx.x * 16;
  const int wz = wid & 1;         // z-half for phase3 roles

  // ---- stage W1pad (K=64): 4 tiles/wave -> 8 frags
  v8h w1r[8];
  #pragma unroll
  for (int nl = 0; nl < 4; ++nl) {
    const int n = wid*4 + nl;
    const float* src = (n < 8) ? (fW1 + (n*16+lr)*33) : (gW1 + ((n-8)*16+lr)*33);
    const float bsv  = (n < 8) ? fb1[n*16+lr] : gb1[(n-8)*16+lr];
    #pragma unroll
    for (int ks = 0; ks < 2; ++ks) {
      v8h w;
      #pragma unroll
      for (int j = 0; j < 8; ++j) {
        const int kp = ks*32 + lg*8 + j;
        float v;
        if (kp < 32)                   v = src[1+kp];
        else if (kp == 32 || kp == 34) v = src[0];
        else if (kp == 33)             v = bsv;
        else                           v = 0.f;
        w[j] = (f16)v;
      }
      w1r[nl*2+ks] = w;
    }
  }
  // ---- stage W2pad (K=160): 2 tiles/wave -> 10 frags
  v8h w2r[10];
  #pragma unroll
  for (int nl = 0; nl < 2; ++nl) {
    const int n = wid*2 + nl;
    const float* src = fW2 + (n*16+lr)*128;
    const float bsv = fb2[n*16+lr];
    #pragma unroll
    for (int ks = 0; ks < 5; ++ks) {
      v8h w;
      #pragma unroll
      for (int j = 0; j < 8; ++j) {
        const int kp = ks*32 + lg*8 + j;
        float v = (kp < 128) ? src[kp] : ((kp == 128) ? bsv : 0.f);
        w[j] = (f16)v;
      }
      w2r[nl*5+ks] = w;
    }
  }
  // ---- stage W3 (drift fW3 + diff gW2, K=160), z-half wz: 10 frags
  v8h w3d[5], w3g[5];
  {
    const float* sd = fW3 + (wz*16+lr)*128;
    const float* sg = gW2 + (wz*16+lr)*128;
    const float bd = fb3[wz*16+lr], bg = gb2[wz*16+lr];
    #pragma unroll
    for (int ks = 0; ks < 5; ++ks) {
      v8h wd, wg;
      #pragma unroll
      for (int j = 0; j < 8; ++j) {
        const int kp = ks*32 + lg*8 + j;
        wd[j] = (f16)((kp < 128) ? sd[kp] : ((kp == 128) ? bd : 0.f));
        wg[j] = (f16)((kp < 128) ? sg[kp] : ((kp == 128) ? bg : 0.f));
      }
      w3d[ks] = wd; w3g[ks] = wg;
    }
  }
  // ---- stage pWpad (K=64): 1 tile/wave -> 2 frags
  v8h pwr[2];
  {
    const float* sp = pW + (wid*16+lr)*32;
    const float bp = pb[wid*16+lr];
    #pragma unroll
    for (int ks = 0; ks < 2; ++ks) {
      v8h w;
      #pragma unroll
      for (int j = 0; j < 8; ++j) {
        const int kp = ks*32 + lg*8 + j;
        w[j] = (f16)((kp < 32) ? sp[kp] : ((kp == 33) ? bp : 0.f));
      }
      pwr[ks] = w;
    }
  }

  // ---- init LDS
  for (int i = t; i < 16*72; i += 256) Xa[i] = (f16)0.f;
  for (int i = t; i < 16*168; i += 256) {
    h1A[i] = (f16)0.f; ghA[i] = (f16)0.f; h2A[i] = (f16)0.f;
  }
  for (int i = t; i < 515; i += 256) tsL[i] = ts[i];
  __syncthreads();
  if (t < 16) {
    Xa[t*72 + 33] = (f16)1.f;
    h1A[t*168 + 128] = (f16)1.f;
    ghA[t*168 + 128] = (f16)1.f;
    h2A[t*168 + 128] = (f16)1.f;
    const float t0 = tsL[0];
    const f16 th = (f16)t0;
    Xa[t*72 + 32] = th;
    Xa[t*72 + 34] = (f16)(t0 - (float)th);
  }
  const v4f zero4 = {0.f, 0.f, 0.f, 0.f};
  v4f zm = zero4;                 // waves 0,1: z-half wid, batch lr, dims lg*4+i
  if (wid < 2) {
    zm = *(const v4f*)&z0[(r0+lr)*Z_ + wid*16 + lg*4];
    v4h a;
    #pragma unroll
    for (int i = 0; i < 4; ++i) a[i] = (f16)zm[i];
    *(v4h*)&Xa[lr*72 + wid*16 + lg*4] = a;
  }
  float loss = 0.f;
  __syncthreads();

  #pragma unroll 1
  for (int l = 0; l < NSTEP; ++l) {
    const float dt  = tsL[l+1] - tsL[l];
    const float sdt = sqrtf(dt);
    const int ln = l + 1;
    const bool ev = ((ln & 1) == 0) && ln >= 2 && ln <= 512;
    const bool od = ((ln & 1) == 1) && ln >= 3 && ln <= 511;

    // prefetch globals used later this step
    v4f dwv = zero4;
    if (wid < 2) dwv = *(const v4f*)&dW[(l*B_ + r0 + lr)*Z_ + wid*16 + lg*4];
    v4f xv = zero4;
    if (ev) xv = *(const v4f*)&xs[(((ln-2)>>1)*B_ + r0 + lr)*D_ + wid*16 + lg*4];

    // ---- GEMM1: [h1; gh]^T = W1pad @ X^T   (4 tiles/wave x 2 k-steps)
    {
      const v8h bx0 = *(const v8h*)&Xa[lr*72 +  0 + lg*8];
      const v8h bx1 = *(const v8h*)&Xa[lr*72 + 32 + lg*8];
      #pragma unroll
      for (int nl = 0; nl < 4; ++nl) {
        v4f acc = __builtin_amdgcn_mfma_f32_16x16x32_f16(w1r[nl*2+0], bx0, zero4, 0, 0, 0);
        acc = __builtin_amdgcn_mfma_f32_16x16x32_f16(w1r[nl*2+1], bx1, acc, 0, 0, 0);
        v4h o;
        #pragma unroll
        for (int i = 0; i < 4; ++i) o[i] = (f16)fmaxf(acc[i], 0.f);
        if (wid < 2) *(v4h*)&h1A[lr*168 + (wid*4+nl)*16 + lg*4] = o;
        else         *(v4h*)&ghA[lr*168 + ((wid-2)*4+nl)*16 + lg*4] = o;
      }
    }
    __syncthreads();   // B1

    // ---- GEMM2: h2^T = W2pad @ h1pad^T   (2 tiles/wave x 5 k-steps)
    {
      v8h bh[5];
      #pragma unroll
      for (int ks = 0; ks < 5; ++ks) bh[ks] = *(const v8h*)&h1A[lr*168 + ks*32 + lg*8];
      #pragma unroll
      for (int nl = 0; nl < 2; ++nl) {
        v4f acc = zero4;
        #pragma unroll
        for (int ks = 0; ks < 5; ++ks)
          acc = __builtin_amdgcn_mfma_f32_16x16x32_f16(w2r[nl*5+ks], bh[ks], acc, 0, 0, 0);
        v4h o;
        #pragma unroll
        for (int i = 0; i < 4; ++i) o[i] = (f16)fmaxf(acc[i], 0.f);
        *(v4h*)&h2A[lr*168 + (wid*2+nl)*16 + lg*4] = o;
      }
    }
    __syncthreads();   // B2

    // ---- phase 3: waves 0,1 do drift+diff for z-half wid; wave 3 writes
    //      next step's t-columns
    if (wid < 2) {
      v4f dac = zero4, fac = zero4;
      #pragma unroll
      for (int ks = 0; ks < 5; ++ks) {
        const v8h b2f = *(const v8h*)&h2A[lr*168 + ks*32 + lg*8];
        const v8h bgf = *(const v8h*)&ghA[lr*168 + ks*32 + lg*8];
        dac = __builtin_amdgcn_mfma_f32_16x16x32_f16(w3d[ks], b2f, dac, 0, 0, 0);
        fac = __builtin_amdgcn_mfma_f32_16x16x32_f16(w3g[ks], bgf, fac, 0, 0, 0);
      }
      #pragma unroll
      for (int i = 0; i < 4; ++i) zm[i] += dac[i]*dt + fac[i]*(sdt*dwv[i]);
      v4h a;
      #pragma unroll
      for (int i = 0; i < 4; ++i) a[i] = (f16)zm[i];
      *(v4h*)&Xa[lr*72 + wid*16 + lg*4] = a;
    } else if (wid == 3 && lg == 0) {
      const float tn = tsL[l+1];
      const f16 th = (f16)tn;
      Xa[lr*72 + 32] = th;
      Xa[lr*72 + 34] = (f16)(tn - (float)th);
    }
    __syncthreads();   // B3

    // ---- proj (1 tile/wave), barrier-free tail: reads only Xa, which is
    //      not rewritten until after next step's B2.
    if (ev || od) {
      const v8h px0 = *(const v8h*)&Xa[lr*72 +  0 + lg*8];
      const v8h px1 = *(const v8h*)&Xa[lr*72 + 32 + lg*8];
      v4f a = __builtin_amdgcn_mfma_f32_16x16x32_f16(pwr[0], px0, zero4, 0, 0, 0);
      v4f p = __builtin_amdgcn_mfma_f32_16x16x32_f16(pwr[1], px1, a, 0, 0, 0);
      if (ev) {
        #pragma unroll
        for (int i = 0; i < 4; ++i) { float d = p[i] - xv[i]; loss = fmaf(d, d, loss); }
      } else {
        float* op = out + 2 + (((ln-3)>>1)*B_ + r0 + lr)*D_ + wid*16 + lg*4;
        *(f2*)&op[0] = (f2){p[0], p[1]};
        *(f2*)&op[2] = (f2){p[2], p[3]};
      }
    }
  }

  #pragma unroll
  for (int s2 = 32; s2 > 0; s2 >>= 1) loss += __shfl_down(loss, s2, 64);
  if (lane == 0) lred[wid] = loss;
  __syncthreads();
  if (t == 0)
    atomicAdd(out + 0, (lred[0] + lred[1] + lred[2] + lred[3]) * (1.f/16777216.f));
}

extern "C" void kernel_launch(void* const* d_in, const int* in_sizes, int n_in,
                              void* d_out, int out_size, void* d_ws, size_t ws_size,
                              hipStream_t stream) {
  (void)in_sizes; (void)n_in; (void)out_size; (void)ws_size;
  const float* xs   = (const float*)d_in[0];
  const float* ts   = (const float*)d_in[1];
  const float* eps  = (const float*)d_in[2];
  const float* dWp  = (const float*)d_in[3];
  const float* Wih  = (const float*)d_in[4];
  const float* Whh  = (const float*)d_in[5];
  const float* bih  = (const float*)d_in[6];
  const float* bhh  = (const float*)d_in[7];
  const float* encW = (const float*)d_in[8];
  const float* encB = (const float*)d_in[9];
  const float* qW   = (const float*)d_in[10];
  const float* qB   = (const float*)d_in[11];
  const float* fW1  = (const float*)d_in[12];
  const float* fb1  = (const float*)d_in[13];
  const float* fW2  = (const float*)d_in[14];
  const float* fb2  = (const float*)d_in[15];
  const float* fW3  = (const float*)d_in[16];
  const float* fb3  = (const float*)d_in[17];
  const float* gW1  = (const float*)d_in[18];
  const float* gb1  = (const float*)d_in[19];
  const float* gW2  = (const float*)d_in[20];
  const float* gb2  = (const float*)d_in[21];
  const float* pW   = (const float*)d_in[22];
  const float* pb   = (const float*)d_in[23];
  const float* pm   = (const float*)d_in[24];
  const float* pls  = (const float*)d_in[25];

  float* out = (float*)d_out;
  float* ws  = (float*)d_ws;
  float* hT = ws;              // 1024*128 floats
  float* z0 = ws + 131072;     // 1024*32 floats

  hipMemsetAsync(d_out, 0, 2*sizeof(float), stream);
  hipLaunchKernelGGL(gru_kernel, dim3(512), dim3(256), 0, stream,
                     xs, Wih, Whh, bih, bhh, hT);
  hipLaunchKernelGGL(enc_kernel, dim3(256), dim3(256), 0, stream,
                     hT, encW, encB, qW, qB, eps, pm, pls, z0, out);
  hipLaunchKernelGGL(sde_mfma_kernel, dim3(64), dim3(256), 0, stream,
                     z0, ts, dWp, xs, fW1, fb1, fW2, fb2, fW3, fb3,
                     gW1, gb1, gW2, gb2, pW, pb, out);
}

// Round 7
// 1269.899 us; speedup vs baseline: 1.7094x; 1.0065x over previous
//
#include <hip/hip_runtime.h>

typedef _Float16 f16;
typedef _Float16 h2 __attribute__((ext_vector_type(2)));
typedef _Float16 h8 __attribute__((ext_vector_type(8)));
typedef _Float16 v8h __attribute__((ext_vector_type(8)));
typedef _Float16 v4h __attribute__((ext_vector_type(4)));
typedef float    f4 __attribute__((ext_vector_type(4)));
typedef float    v4f __attribute__((ext_vector_type(4)));
typedef float    f2 __attribute__((ext_vector_type(2)));

#define S_  256
#define B_  1024
#define D_  64
#define H_  128
#define Z_  32
#define BD_ (B_*D_)
#define NSTEP 514

__device__ __forceinline__ h8 ld8(const float* p) {   // 32B-aligned src
  f4 a = *(const f4*)p;
  f4 b = *(const f4*)(p + 4);
  h8 w;
  w[0]=(f16)a[0]; w[1]=(f16)a[1]; w[2]=(f16)a[2]; w[3]=(f16)a[3];
  w[4]=(f16)b[0]; w[5]=(f16)b[1]; w[6]=(f16)b[2]; w[7]=(f16)b[3];
  return w;
}

__device__ __forceinline__ float sigm(float x) { return 1.f / (1.f + __expf(-x)); }
__device__ __forceinline__ float tanh_(float x) {
  float e = __expf(-2.f * fabsf(x));
  float t = (1.f - e) / (1.f + e);
  return copysignf(t, x);
}

// ---------------------------------------------------------------------------
// GRU round-7: MFMA rewrite (fragment layouts HW-verified by r5/r6 sde).
// 64 blocks x 4 waves, 16 batch rows/block. Wave w owns neuron rows
// w*32..w*32+31 of ALL gates (r: rows n, z: 128+n, nh/nx: 256+n) -> the gate
// combine is entirely lane-local (C layout: col=batch=lane&15,
// row=(lane>>4)*4+i). Per wave/step: 4 ds_read_b128 (h B-frags, shared by
// all tiles) + 36 MFMA (8 indep chains) + gate VALU + 2 ds_write_b64 +
// ONE barrier (h double-buffered [16][136] f16; pad 8 -> 16B-aligned rows,
// 2-way bank aliasing = free). x loaded straight to B-frags from global
// (wave reads contiguous 4KB), prefetched one step ahead. h masters fp32
// in regs; biases folded in VALU (per-lane v4f consts).
// ---------------------------------------------------------------------------
__global__ __launch_bounds__(256, 1) void gru_mfma_kernel(
    const float* __restrict__ xs, const float* __restrict__ Wih,
    const float* __restrict__ Whh, const float* __restrict__ bih,
    const float* __restrict__ bhh, float* __restrict__ hT)
{
  __shared__ f16 hB[2][16][136];   // [buf][batch][h + pad8]

  const int t    = threadIdx.x;
  const int wid  = t >> 6;
  const int lane = t & 63;
  const int lr = lane & 15;        // A row / batch col
  const int lg = lane >> 4;        // k-group / C row-group
  const int r0 = blockIdx.x * 16;

  // ---- weight A-frags: row = lr, k = ks*32 + lg*8 + j
  v8h whhR[2][4], whhZ[2][4], whhN[2][4];
  v8h wihR[2][2], wihZ[2][2], wihN[2][2];
  #pragma unroll
  for (int tt = 0; tt < 2; ++tt) {
    const int nr = wid*32 + tt*16 + lr;
    #pragma unroll
    for (int ks = 0; ks < 4; ++ks) {
      whhR[tt][ks] = ld8(Whh + (      nr)*H_ + ks*32 + lg*8);
      whhZ[tt][ks] = ld8(Whh + (128 + nr)*H_ + ks*32 + lg*8);
      whhN[tt][ks] = ld8(Whh + (256 + nr)*H_ + ks*32 + lg*8);
    }
    #pragma unroll
    for (int ks = 0; ks < 2; ++ks) {
      wihR[tt][ks] = ld8(Wih + (      nr)*D_ + ks*32 + lg*8);
      wihZ[tt][ks] = ld8(Wih + (128 + nr)*D_ + ks*32 + lg*8);
      wihN[tt][ks] = ld8(Wih + (256 + nr)*D_ + ks*32 + lg*8);
    }
  }
  // ---- per-lane gate bias consts (neurons wid*32 + tt*16 + lg*4 + i)
  v4f birh[2], bizh[2], binv[2], bhnv[2];
  #pragma unroll
  for (int tt = 0; tt < 2; ++tt) {
    const int nb = wid*32 + tt*16 + lg*4;
    v4f a = *(const v4f*)&bih[nb],     b = *(const v4f*)&bhh[nb];
    v4f c = *(const v4f*)&bih[128+nb], d = *(const v4f*)&bhh[128+nb];
    birh[tt] = a + b;
    bizh[tt] = c + d;
    binv[tt] = *(const v4f*)&bih[256+nb];
    bhnv[tt] = *(const v4f*)&bhh[256+nb];
  }

  for (int i = t; i < 16*136; i += 256) ((f16*)hB[0])[i] = (f16)0.f;
  v4f hm[2] = { {0.f,0.f,0.f,0.f}, {0.f,0.f,0.f,0.f} };  // fp32 h masters
  const v4f zero4 = {0.f, 0.f, 0.f, 0.f};

  // x B-frags for step 0 (x_rev[0] = xs[S-1])
  v8h bx0 = ld8(xs + (S_-1)*BD_ + (r0+lr)*D_ + lg*8);
  v8h bx1 = ld8(xs + (S_-1)*BD_ + (r0+lr)*D_ + 32 + lg*8);
  __syncthreads();

  int p = 0;
  #pragma unroll 1
  for (int s = 0; s < S_; ++s) {
    v8h nx0 = bx0, nx1 = bx1;
    if (s < S_-1) {
      const float* xp = xs + (S_-2-s)*BD_ + (r0+lr)*D_;
      nx0 = ld8(xp + lg*8);
      nx1 = ld8(xp + 32 + lg*8);
    }
    v8h bh[4];
    #pragma unroll
    for (int ks = 0; ks < 4; ++ks)
      bh[ks] = *(const v8h*)&hB[p][lr][ks*32 + lg*8];

    #pragma unroll
    for (int tt = 0; tt < 2; ++tt) {
      v4f ar  = __builtin_amdgcn_mfma_f32_16x16x32_f16(wihR[tt][0], bx0, zero4, 0,0,0);
      v4f az  = __builtin_amdgcn_mfma_f32_16x16x32_f16(wihZ[tt][0], bx0, zero4, 0,0,0);
      v4f anx = __builtin_amdgcn_mfma_f32_16x16x32_f16(wihN[tt][0], bx0, zero4, 0,0,0);
      ar  = __builtin_amdgcn_mfma_f32_16x16x32_f16(wihR[tt][1], bx1, ar,  0,0,0);
      az  = __builtin_amdgcn_mfma_f32_16x16x32_f16(wihZ[tt][1], bx1, az,  0,0,0);
      anx = __builtin_amdgcn_mfma_f32_16x16x32_f16(wihN[tt][1], bx1, anx, 0,0,0);
      v4f anh = zero4;
      #pragma unroll
      for (int ks = 0; ks < 4; ++ks) {
        ar  = __builtin_amdgcn_mfma_f32_16x16x32_f16(whhR[tt][ks], bh[ks], ar,  0,0,0);
        az  = __builtin_amdgcn_mfma_f32_16x16x32_f16(whhZ[tt][ks], bh[ks], az,  0,0,0);
        anh = __builtin_amdgcn_mfma_f32_16x16x32_f16(whhN[tt][ks], bh[ks], anh, 0,0,0);
      }
      v4h o;
      #pragma unroll
      for (int i = 0; i < 4; ++i) {
        float r  = sigm(ar[i] + birh[tt][i]);
        float zg = sigm(az[i] + bizh[tt][i]);
        float n  = tanh_(anx[i] + binv[tt][i] + r*(anh[i] + bhnv[tt][i]));
        hm[tt][i] = (1.f - zg)*n + zg*hm[tt][i];
        o[i] = (f16)hm[tt][i];
      }
      *(v4h*)&hB[p^1][lr][wid*32 + tt*16 + lg*4] = o;
    }
    __syncthreads();
    p ^= 1;
    bx0 = nx0; bx1 = nx1;
  }

  #pragma unroll
  for (int tt = 0; tt < 2; ++tt)
    *(v4f*)&hT[(r0+lr)*H_ + wid*32 + tt*16 + lg*4] = hm[tt];
}

// ---------------------------------------------------------------------------
// Encoder head (unchanged; tiny): 256 blocks x 4 rows.
// ---------------------------------------------------------------------------
__global__ __launch_bounds__(256) void enc_kernel(
    const float* __restrict__ hT, const float* __restrict__ encW,
    const float* __restrict__ encB, const float* __restrict__ qW,
    const float* __restrict__ qB, const float* __restrict__ eps,
    const float* __restrict__ pm, const float* __restrict__ pls,
    float* __restrict__ z0, float* __restrict__ out)
{
  __shared__ float hTl[4][128];
  __shared__ float ctx[4][64];
  __shared__ float ql[4][64];
  const int t = threadIdx.x;
  const int b0 = blockIdx.x * 4;
  const int lb = t >> 6, j = t & 63;

  for (int i = t; i < 512; i += 256) hTl[i>>7][i&127] = hT[b0*H_ + i];
  __syncthreads();

  float acc = encB[j];
  #pragma unroll
  for (int k = 0; k < 128; k += 4) {
    f4 w = *(const f4*)&encW[j*128 + k];
    acc += hTl[lb][k]*w[0] + hTl[lb][k+1]*w[1] + hTl[lb][k+2]*w[2] + hTl[lb][k+3]*w[3];
  }
  ctx[lb][j] = acc;
  __syncthreads();

  float q = qB[j];
  #pragma unroll
  for (int k = 0; k < 64; k += 4) {
    f4 w = *(const f4*)&qW[j*64 + k];
    q += ctx[lb][k]*w[0] + ctx[lb][k+1]*w[1] + ctx[lb][k+2]*w[2] + ctx[lb][k+3]*w[3];
  }
  ql[lb][j] = q;
  __syncthreads();

  float kl = 0.f;
  if (j < 32) {
    float mean = ql[lb][j], ls = ql[lb][j+32];
    z0[(b0+lb)*Z_ + j] = mean + __expf(ls)*eps[(b0+lb)*Z_ + j];
    float pmj = pm[j], plsj = pls[j];
    float dm = mean - pmj;
    kl = plsj - ls + (__expf(2.f*ls) + dm*dm) / (2.f*__expf(2.f*plsj)) - 0.5f;
  }
  #pragma unroll
  for (int s2 = 32; s2 > 0; s2 >>= 1) kl += __shfl_down(kl, s2, 64);
  if (j == 0) atomicAdd(out + 1, kl * (1.f/1024.f));
}

// ---------------------------------------------------------------------------
// SDE: round-6 MFMA kernel (measured 584us). UNCHANGED this round.
// ---------------------------------------------------------------------------
__global__ __launch_bounds__(256, 1) void sde_mfma_kernel(
    const float* __restrict__ z0, const float* __restrict__ ts,
    const float* __restrict__ dW, const float* __restrict__ xs,
    const float* __restrict__ fW1, const float* __restrict__ fb1,
    const float* __restrict__ fW2, const float* __restrict__ fb2,
    const float* __restrict__ fW3, const float* __restrict__ fb3,
    const float* __restrict__ gW1, const float* __restrict__ gb1,
    const float* __restrict__ gW2, const float* __restrict__ gb2,
    const float* __restrict__ pW, const float* __restrict__ pb,
    float* __restrict__ out)
{
  __shared__ f16 Xa[16*72];       // [batch][72]: 0..31 z, 32 t, 33 one, 34 t-resid
  __shared__ f16 h1A[16*168];     // [batch][168]: 0..127 h1, 128 one, rest 0
  __shared__ f16 ghA[16*168];
  __shared__ f16 h2A[16*168];
  __shared__ float tsL[516];
  __shared__ float lred[4];

  const int t    = threadIdx.x;
  const int wid  = t >> 6;
  const int lane = t & 63;
  const int lr = lane & 15;       // tile-row (A) / batch-col (B/C)
  const int lg = lane >> 4;       // k-group / C row-group
  const int r0 = blockIdx.x * 16;
  const int wz = wid & 1;         // z-half for phase3 roles

  // ---- stage W1pad (K=64): 4 tiles/wave -> 8 frags
  v8h w1r[8];
  #pragma unroll
  for (int nl = 0; nl < 4; ++nl) {
    const int n = wid*4 + nl;
    const float* src = (n < 8) ? (fW1 + (n*16+lr)*33) : (gW1 + ((n-8)*16+lr)*33);
    const float bsv  = (n < 8) ? fb1[n*16+lr] : gb1[(n-8)*16+lr];
    #pragma unroll
    for (int ks = 0; ks < 2; ++ks) {
      v8h w;
      #pragma unroll
      for (int j = 0; j < 8; ++j) {
        const int kp = ks*32 + lg*8 + j;
        float v;
        if (kp < 32)                   v = src[1+kp];
        else if (kp == 32 || kp == 34) v = src[0];
        else if (kp == 33)             v = bsv;
        else                           v = 0.f;
        w[j] = (f16)v;
      }
      w1r[nl*2+ks] = w;
    }
  }
  // ---- stage W2pad (K=160): 2 tiles/wave -> 10 frags
  v8h w2r[10];
  #pragma unroll
  for (int nl = 0; nl < 2; ++nl) {
    const int n = wid*2 + nl;
    const float* src = fW2 + (n*16+lr)*128;
    const float bsv = fb2[n*16+lr];
    #pragma unroll
    for (int ks = 0; ks < 5; ++ks) {
      v8h w;
      #pragma unroll
      for (int j = 0; j < 8; ++j) {
        const int kp = ks*32 + lg*8 + j;
        float v = (kp < 128) ? src[kp] : ((kp == 128) ? bsv : 0.f);
        w[j] = (f16)v;
      }
      w2r[nl*5+ks] = w;
    }
  }
  // ---- stage W3 (drift fW3 + diff gW2, K=160), z-half wz: 10 frags
  v8h w3d[5], w3g[5];
  {
    const float* sd = fW3 + (wz*16+lr)*128;
    const float* sg = gW2 + (wz*16+lr)*128;
    const float bd = fb3[wz*16+lr], bg = gb2[wz*16+lr];
    #pragma unroll
    for (int ks = 0; ks < 5; ++ks) {
      v8h wd, wg;
      #pragma unroll
      for (int j = 0; j < 8; ++j) {
        const int kp = ks*32 + lg*8 + j;
        wd[j] = (f16)((kp < 128) ? sd[kp] : ((kp == 128) ? bd : 0.f));
        wg[j] = (f16)((kp < 128) ? sg[kp] : ((kp == 128) ? bg : 0.f));
      }
      w3d[ks] = wd; w3g[ks] = wg;
    }
  }
  // ---- stage pWpad (K=64): 1 tile/wave -> 2 frags
  v8h pwr[2];
  {
    const float* sp = pW + (wid*16+lr)*32;
    const float bp = pb[wid*16+lr];
    #pragma unroll
    for (int ks = 0; ks < 2; ++ks) {
      v8h w;
      #pragma unroll
      for (int j = 0; j < 8; ++j) {
        const int kp = ks*32 + lg*8 + j;
        w[j] = (f16)((kp < 32) ? sp[kp] : ((kp == 33) ? bp : 0.f));
      }
      pwr[ks] = w;
    }
  }

  // ---- init LDS
  for (int i = t; i < 16*72; i += 256) Xa[i] = (f16)0.f;
  for (int i = t; i < 16*168; i += 256) {
    h1A[i] = (f16)0.f; ghA[i] = (f16)0.f; h2A[i] = (f16)0.f;
  }
  for (int i = t; i < 515; i += 256) tsL[i] = ts[i];
  __syncthreads();
  if (t < 16) {
    Xa[t*72 + 33] = (f16)1.f;
    h1A[t*168 + 128] = (f16)1.f;
    ghA[t*168 + 128] = (f16)1.f;
    h2A[t*168 + 128] = (f16)1.f;
    const float t0 = tsL[0];
    const f16 th = (f16)t0;
    Xa[t*72 + 32] = th;
    Xa[t*72 + 34] = (f16)(t0 - (float)th);
  }
  const v4f zero4 = {0.f, 0.f, 0.f, 0.f};
  v4f zm = zero4;                 // waves 0,1: z-half wid, batch lr, dims lg*4+i
  if (wid < 2) {
    zm = *(const v4f*)&z0[(r0+lr)*Z_ + wid*16 + lg*4];
    v4h a;
    #pragma unroll
    for (int i = 0; i < 4; ++i) a[i] = (f16)zm[i];
    *(v4h*)&Xa[lr*72 + wid*16 + lg*4] = a;
  }
  float loss = 0.f;
  __syncthreads();

  #pragma unroll 1
  for (int l = 0; l < NSTEP; ++l) {
    const float dt  = tsL[l+1] - tsL[l];
    const float sdt = sqrtf(dt);
    const int ln = l + 1;
    const bool ev = ((ln & 1) == 0) && ln >= 2 && ln <= 512;
    const bool od = ((ln & 1) == 1) && ln >= 3 && ln <= 511;

    // prefetch globals used later this step
    v4f dwv = zero4;
    if (wid < 2) dwv = *(const v4f*)&dW[(l*B_ + r0 + lr)*Z_ + wid*16 + lg*4];
    v4f xv = zero4;
    if (ev) xv = *(const v4f*)&xs[(((ln-2)>>1)*B_ + r0 + lr)*D_ + wid*16 + lg*4];

    // ---- GEMM1: [h1; gh]^T = W1pad @ X^T   (4 tiles/wave x 2 k-steps)
    {
      const v8h bx0 = *(const v8h*)&Xa[lr*72 +  0 + lg*8];
      const v8h bx1 = *(const v8h*)&Xa[lr*72 + 32 + lg*8];
      #pragma unroll
      for (int nl = 0; nl < 4; ++nl) {
        v4f acc = __builtin_amdgcn_mfma_f32_16x16x32_f16(w1r[nl*2+0], bx0, zero4, 0, 0, 0);
        acc = __builtin_amdgcn_mfma_f32_16x16x32_f16(w1r[nl*2+1], bx1, acc, 0, 0, 0);
        v4h o;
        #pragma unroll
        for (int i = 0; i < 4; ++i) o[i] = (f16)fmaxf(acc[i], 0.f);
        if (wid < 2) *(v4h*)&h1A[lr*168 + (wid*4+nl)*16 + lg*4] = o;
        else         *(v4h*)&ghA[lr*168 + ((wid-2)*4+nl)*16 + lg*4] = o;
      }
    }
    __syncthreads();   // B1

    // ---- GEMM2: h2^T = W2pad @ h1pad^T   (2 tiles/wave x 5 k-steps)
    {
      v8h bh[5];
      #pragma unroll
      for (int ks = 0; ks < 5; ++ks) bh[ks] = *(const v8h*)&h1A[lr*168 + ks*32 + lg*8];
      #pragma unroll
      for (int nl = 0; nl < 2; ++nl) {
        v4f acc = zero4;
        #pragma unroll
        for (int ks = 0; ks < 5; ++ks)
          acc = __builtin_amdgcn_mfma_f32_16x16x32_f16(w2r[nl*5+ks], bh[ks], acc, 0, 0, 0);
        v4h o;
        #pragma unroll
        for (int i = 0; i < 4; ++i) o[i] = (f16)fmaxf(acc[i], 0.f);
        *(v4h*)&h2A[lr*168 + (wid*2+nl)*16 + lg*4] = o;
      }
    }
    __syncthreads();   // B2

    // ---- phase 3: waves 0,1 do drift+diff for z-half wid; wave 3 writes
    //      next step's t-columns
    if (wid < 2) {
      v4f dac = zero4, fac = zero4;
      #pragma unroll
      for (int ks = 0; ks < 5; ++ks) {
        const v8h b2f = *(const v8h*)&h2A[lr*168 + ks*32 + lg*8];
        const v8h bgf = *(const v8h*)&ghA[lr*168 + ks*32 + lg*8];
        dac = __builtin_amdgcn_mfma_f32_16x16x32_f16(w3d[ks], b2f, dac, 0, 0, 0);
        fac = __builtin_amdgcn_mfma_f32_16x16x32_f16(w3g[ks], bgf, fac, 0, 0, 0);
      }
      #pragma unroll
      for (int i = 0; i < 4; ++i) zm[i] += dac[i]*dt + fac[i]*(sdt*dwv[i]);
      v4h a;
      #pragma unroll
      for (int i = 0; i < 4; ++i) a[i] = (f16)zm[i];
      *(v4h*)&Xa[lr*72 + wid*16 + lg*4] = a;
    } else if (wid == 3 && lg == 0) {
      const float tn = tsL[l+1];
      const f16 th = (f16)tn;
      Xa[lr*72 + 32] = th;
      Xa[lr*72 + 34] = (f16)(tn - (float)th);
    }
    __syncthreads();   // B3

    // ---- proj (1 tile/wave), barrier-free tail: reads only Xa, which is
    //      not rewritten until after next step's B2.
    if (ev || od) {
      const v8h px0 = *(const v8h*)&Xa[lr*72 +  0 + lg*8];
      const v8h px1 = *(const v8h*)&Xa[lr*72 + 32 + lg*8];
      v4f a = __builtin_amdgcn_mfma_f32_16x16x32_f16(pwr[0], px0, zero4, 0, 0, 0);
      v4f p = __builtin_amdgcn_mfma_f32_16x16x32_f16(pwr[1], px1, a, 0, 0, 0);
      if (ev) {
        #pragma unroll
        for (int i = 0; i < 4; ++i) { float d = p[i] - xv[i]; loss = fmaf(d, d, loss); }
      } else {
        float* op = out + 2 + (((ln-3)>>1)*B_ + r0 + lr)*D_ + wid*16 + lg*4;
        *(f2*)&op[0] = (f2){p[0], p[1]};
        *(f2*)&op[2] = (f2){p[2], p[3]};
      }
    }
  }

  #pragma unroll
  for (int s2 = 32; s2 > 0; s2 >>= 1) loss += __shfl_down(loss, s2, 64);
  if (lane == 0) lred[wid] = loss;
  __syncthreads();
  if (t == 0)
    atomicAdd(out + 0, (lred[0] + lred[1] + lred[2] + lred[3]) * (1.f/16777216.f));
}

extern "C" void kernel_launch(void* const* d_in, const int* in_sizes, int n_in,
                              void* d_out, int out_size, void* d_ws, size_t ws_size,
                              hipStream_t stream) {
  (void)in_sizes; (void)n_in; (void)out_size; (void)ws_size;
  const float* xs   = (const float*)d_in[0];
  const float* ts   = (const float*)d_in[1];
  const float* eps  = (const float*)d_in[2];
  const float* dWp  = (const float*)d_in[3];
  const float* Wih  = (const float*)d_in[4];
  const float* Whh  = (const float*)d_in[5];
  const float* bih  = (const float*)d_in[6];
  const float* bhh  = (const float*)d_in[7];
  const float* encW = (const float*)d_in[8];
  const float* encB = (const float*)d_in[9];
  const float* qW   = (const float*)d_in[10];
  const float* qB   = (const float*)d_in[11];
  const float* fW1  = (const float*)d_in[12];
  const float* fb1  = (const float*)d_in[13];
  const float* fW2  = (const float*)d_in[14];
  const float* fb2  = (const float*)d_in[15];
  const float* fW3  = (const float*)d_in[16];
  const float* fb3  = (const float*)d_in[17];
  const float* gW1  = (const float*)d_in[18];
  const float* gb1  = (const float*)d_in[19];
  const float* gW2  = (const float*)d_in[20];
  const float* gb2  = (const float*)d_in[21];
  const float* pW   = (const float*)d_in[22];
  const float* pb   = (const float*)d_in[23];
  const float* pm   = (const float*)d_in[24];
  const float* pls  = (const float*)d_in[25];

  float* out = (float*)d_out;
  float* ws  = (float*)d_ws;
  float* hT = ws;              // 1024*128 floats
  float* z0 = ws + 131072;     // 1024*32 floats

  hipMemsetAsync(d_out, 0, 2*sizeof(float), stream);
  hipLaunchKernelGGL(gru_mfma_kernel, dim3(64), dim3(256), 0, stream,
                     xs, Wih, Whh, bih, bhh, hT);
  hipLaunchKernelGGL(enc_kernel, dim3(256), dim3(256), 0, stream,
                     hT, encW, encB, qW, qB, eps, pm, pls, z0, out);
  hipLaunchKernelGGL(sde_mfma_kernel, dim3(64), dim3(256), 0, stream,
                     z0, ts, dWp, xs, fW1, fb1, fW2, fb2, fW3, fb3,
                     gW1, gb1, gW2, gb2, pW, pb, out);
}